// Round 1
// 1031.294 us; speedup vs baseline: 1.0262x; 1.0262x over previous
//
#include <hip/hip_runtime.h>
#include <math.h>

#define L2E 1.4426950408889634f   // log2(e)
#define LN2 0.6931471805599453f   // ln(2)

// Fast exp2: raw v_exp_f32 (inputs here are <= 0, no denormal-input concerns).
#if __has_builtin(__builtin_amdgcn_exp2f)
#define EXP2(x) __builtin_amdgcn_exp2f(x)
#else
#define EXP2(x) __expf((x) * LN2)
#endif

// (m, s) logsumexp-merge in the log2 domain: s' = s*2^(m-mn) + s2*2^(m2-mn).
__device__ __forceinline__ void combine2(float& m, float& s, float m2, float s2) {
    float mn = fmaxf(m, m2);
    s = s * EXP2(m - mn) + s2 * EXP2(m2 - mn);
    m = mn;
}

// One block per row. 256 threads stream the row as chunks of 8 float4 per
// thread (2048 vec4 per block-iteration). Branchless online softmax: per
// 32-element chunk compute the chunk max, then ONE rescale + 32 exp2.
// All state kept in the log2 domain (m = max(x)*log2e, s = sum 2^(x*log2e - m)).
__global__ __launch_bounds__(256)
void ce_tier_kernel(const float* __restrict__ in,
                    const int* __restrict__ labels,
                    float* __restrict__ out,
                    int vocab) {
    const int row = blockIdx.x;
    const long long base = (long long)row * vocab;
    const float* rp = in + base;

    // Peel to 16B alignment (row stride 50257 floats is odd).
    const int head = (int)((4 - (base & 3)) & 3);
    const int nvec = (vocab - head) >> 2;            // # aligned float4s
    const int tail_start = head + (nvec << 2);
    const int tid = threadIdx.x;

    const float4* vp = (const float4*)(rp + head);

    float m = -INFINITY;   // running max, log2 domain
    float s = 0.0f;        // running sum of 2^(y - m)

    // Full chunks: 2048 vec4 per iteration (256 threads x 8 vec4).
    const int nfull = nvec >> 11;
    for (int c = 0; c < nfull; ++c) {
        const float4* bp = vp + (c << 11) + tid;
        float4 v[8];
        #pragma unroll
        for (int j = 0; j < 8; ++j) v[j] = bp[j << 8];   // 8 loads in flight

        float cm = fmaxf(fmaxf(v[0].x, v[0].y), fmaxf(v[0].z, v[0].w));
        #pragma unroll
        for (int j = 1; j < 8; ++j)
            cm = fmaxf(cm, fmaxf(fmaxf(v[j].x, v[j].y), fmaxf(v[j].z, v[j].w)));

        const float mn = fmaxf(m, cm * L2E);
        const float sc = EXP2(m - mn);       // -inf - finite -> 2^-inf = 0 (ok)
        float cs0 = 0.0f, cs1 = 0.0f;
        #pragma unroll
        for (int j = 0; j < 8; ++j) {
            cs0 += EXP2(fmaf(v[j].x, L2E, -mn)) + EXP2(fmaf(v[j].y, L2E, -mn));
            cs1 += EXP2(fmaf(v[j].z, L2E, -mn)) + EXP2(fmaf(v[j].w, L2E, -mn));
        }
        s = fmaf(s, sc, cs0 + cs1);
        m = mn;
    }

    // Remainder vec4s (branchless per-vec4 combine; <=2 iters/thread here).
    for (int i = (nfull << 11) + tid; i < nvec; i += 256) {
        float4 v = vp[i];
        float m4 = fmaxf(fmaxf(v.x, v.y), fmaxf(v.z, v.w)) * L2E;
        float mn = fmaxf(m, m4);
        float sc = EXP2(m - mn);
        float cs = EXP2(fmaf(v.x, L2E, -mn)) + EXP2(fmaf(v.y, L2E, -mn))
                 + EXP2(fmaf(v.z, L2E, -mn)) + EXP2(fmaf(v.w, L2E, -mn));
        s = fmaf(s, sc, cs);
        m = mn;
    }

    // Head/tail scalars (<=3 each) — thread 0 only; its m is already finite
    // (every thread processed >= nfull*8 >= 48 vec4s at vocab=50257).
    if (tid == 0) {
        for (int i = 0; i < head; ++i) {
            float y = rp[i] * L2E;
            float mn = fmaxf(m, y);
            s = s * EXP2(m - mn) + EXP2(y - mn);
            m = mn;
        }
        for (int i = tail_start; i < vocab; ++i) {
            float y = rp[i] * L2E;
            float mn = fmaxf(m, y);
            s = s * EXP2(m - mn) + EXP2(y - mn);
            m = mn;
        }
    }

    // Wave (64-lane) butterfly-down reduction of (m, s).
    #pragma unroll
    for (int off = 32; off >= 1; off >>= 1) {
        float m2 = __shfl_down(m, off, 64);
        float s2 = __shfl_down(s, off, 64);
        combine2(m, s, m2, s2);
    }

    __shared__ float sm[4], ss[4];
    const int wave = tid >> 6;
    const int lane = tid & 63;
    if (lane == 0) { sm[wave] = m; ss[wave] = s; }
    __syncthreads();

    if (tid == 0) {
        float M = sm[0], S = ss[0];
        #pragma unroll
        for (int w = 1; w < 4; ++w) combine2(M, S, sm[w], ss[w]);

        const int lbl = labels[row];
        const float picked = rp[lbl];
        // logsumexp(x) = ln2 * (M + log2(S)) in the log2 domain.
        const float loss = fmaf(LN2, M + __log2f(S), -picked);
        const int tier = (lbl >= 100) + (lbl >= 1000) + (lbl >= 10000);
        atomicAdd(out + tier, loss);        // values[tier]
        atomicAdd(out + 4 + tier, 1.0f);    // counts[tier]
    }
}

// Empty-tier substitution: count==0 -> 1.0 (loss already 0 from memset).
__global__ void fixup_counts(float* __restrict__ out) {
    int i = threadIdx.x;
    if (i < 4 && out[4 + i] == 0.0f) out[4 + i] = 1.0f;
}

extern "C" void kernel_launch(void* const* d_in, const int* in_sizes, int n_in,
                              void* d_out, int out_size, void* d_ws, size_t ws_size,
                              hipStream_t stream) {
    const float* in = (const float*)d_in[0];
    const int* labels = (const int*)d_in[1];
    float* out = (float*)d_out;

    const int n = in_sizes[1];                 // 4096 rows
    const int vocab = in_sizes[0] / n;         // 50257

    hipMemsetAsync(out, 0, (size_t)out_size * sizeof(float), stream);
    ce_tier_kernel<<<n, 256, 0, stream>>>(in, labels, out, vocab);
    fixup_counts<<<1, 64, 0, stream>>>(out);
}